// Round 14
// baseline (1079.243 us; speedup 1.0000x reference)
//
#include <hip/hip_runtime.h>
#include <cstdint>
#include <cstddef>

typedef unsigned long long u64;
typedef __attribute__((ext_vector_type(8))) short bf16x8;
typedef __attribute__((ext_vector_type(4))) float f32x4;
typedef __attribute__((ext_vector_type(2))) float f32x2;

#define NB 16
#define NC 64
#define NN 4096
#define NM 1024
#define NK 32
#define KP1 104
#define KP2 72

// ---------- DPP wave-reduction helpers ----------

template <int C>
__device__ __forceinline__ float dppf(float x, float ident) {
  return __int_as_float(__builtin_amdgcn_update_dpp(
      __float_as_int(ident), __float_as_int(x), C, 0xf, 0xf, false));
}

template <int C>
__device__ __forceinline__ unsigned dppu(unsigned x, unsigned ident) {
  return (unsigned)__builtin_amdgcn_update_dpp(
      (int)ident, (int)x, C, 0xf, 0xf, false);
}

__device__ __forceinline__ float wave_fmax(float x) {
  const float I = __int_as_float(0xff800000);  // -inf
  x = fmaxf(x, dppf<0x111>(x, I));
  x = fmaxf(x, dppf<0x112>(x, I));
  x = fmaxf(x, dppf<0x114>(x, I));
  x = fmaxf(x, dppf<0x118>(x, I));
  x = fmaxf(x, dppf<0x142>(x, I));  // row_bcast:15
  x = fmaxf(x, dppf<0x143>(x, I));  // row_bcast:31
  return __int_as_float(__builtin_amdgcn_readlane(__float_as_int(x), 63));
}

__device__ __forceinline__ float wave_fmin(float x) {
  const float I = __int_as_float(0x7f800000);  // +inf
  x = fminf(x, dppf<0x111>(x, I));
  x = fminf(x, dppf<0x112>(x, I));
  x = fminf(x, dppf<0x114>(x, I));
  x = fminf(x, dppf<0x118>(x, I));
  x = fminf(x, dppf<0x142>(x, I));
  x = fminf(x, dppf<0x143>(x, I));
  return __int_as_float(__builtin_amdgcn_readlane(__float_as_int(x), 63));
}

__device__ __forceinline__ unsigned wave_umin(unsigned x) {
  const unsigned I = 0xFFFFFFFFu;
  unsigned t;
  t = dppu<0x111>(x, I); x = x < t ? x : t;
  t = dppu<0x112>(x, I); x = x < t ? x : t;
  t = dppu<0x114>(x, I); x = x < t ? x : t;
  t = dppu<0x118>(x, I); x = x < t ? x : t;
  t = dppu<0x142>(x, I); x = x < t ? x : t;
  t = dppu<0x143>(x, I); x = x < t ? x : t;
  return (unsigned)__builtin_amdgcn_readlane((int)x, 63);
}

// max over 16-lane group via DPP row_ror 8/4/2/1
#define RED16(m) { m = fmaxf(m, dppf<0x128>(m, 0.f)); m = fmaxf(m, dppf<0x124>(m, 0.f)); \
                   m = fmaxf(m, dppf<0x122>(m, 0.f)); m = fmaxf(m, dppf<0x121>(m, 0.f)); }

// f32 -> bf16 (RNE), pack pair
__device__ __forceinline__ unsigned short f2bf(float f) {
  unsigned u = __float_as_uint(f);
  return (unsigned short)((u + 0x7FFFu + ((u >> 16) & 1u)) >> 16);
}
__device__ __forceinline__ int pk(float a, float b) {
  return (int)f2bf(a) | ((int)f2bf(b) << 16);
}

// ---------- kernel A: FUSED fps + transpose + w_prep (R13, verbatim) ----------

__global__ __launch_bounds__(256) void fps_fused(
    const float* __restrict__ loc, float* __restrict__ out_setloc,
    const float* __restrict__ feat, float* __restrict__ featT,
    const float* __restrict__ W1, const float* __restrict__ W2,
    const float* __restrict__ W3, short* __restrict__ w1b,
    short* __restrict__ w2b, short* __restrict__ w3b) {
  __shared__ __align__(16) float lx[NN];
  __shared__ __align__(16) float ly[NN];
  __shared__ __align__(16) float lz[NN];
  __shared__ float4 red[2][4];
  const int tid = threadIdx.x;

  if (blockIdx.x >= 16) {
    if (blockIdx.x < 2064) {
      // transpose role: 2048 elements per block
      const int base = (blockIdx.x - 16) * 2048;
#pragma unroll
      for (int it = 0; it < 8; ++it) {
        int g = base + it * 256 + tid;
        int c = g & 63;
        int n = (g >> 6) & 4095;
        int b = g >> 18;
        featT[g] = feat[((size_t)(b * NC + c)) * NN + n];
      }
    } else {
      // w_prep role: 20480 elements over 10 blocks
      const int base = (blockIdx.x - 2064) * 2048;
#pragma unroll
      for (int it = 0; it < 8; ++it) {
        int gg = base + it * 256 + tid;
        if (gg < 64 * KP1) {
          int r = gg / KP1, k = gg - r * KP1;
          w1b[gg] = (k < 67) ? (short)f2bf(W1[r * 67 + k]) : (short)0;
        } else if (gg < 64 * KP1 + 64 * KP2) {
          int g2 = gg - 64 * KP1;
          int r = g2 / KP2, k = g2 - r * KP2;
          w2b[g2] = (k < 64) ? (short)f2bf(W2[r * 64 + k]) : (short)0;
        } else if (gg < 64 * KP1 + 64 * KP2 + 128 * KP2) {
          int g3 = gg - 64 * KP1 - 64 * KP2;
          int r = g3 / KP2, k = g3 - r * KP2;
          w3b[g3] = (k < 64) ? (short)f2bf(W3[r * 64 + k]) : (short)0;
        }
      }
    }
    return;
  }

  // ---- fps role: one batch per block ----
  {
    // CRITICAL: no fma contraction -- the discrete argmax must reproduce
    // numpy's exact per-op rounding (mul, add, add; left-assoc).
#pragma clang fp contract(off)
    const int b = blockIdx.x;
    const int lane = tid & 63, wid = tid >> 6;
    const float* Lx = loc + (size_t)b * 3 * NN;
    const float* Ly = Lx + NN;
    const float* Lz = Ly + NN;
    const int p0 = tid * 16;
    f32x2 px2[8], py2[8], pz2[8], dist2[8];
#pragma unroll
    for (int j4 = 0; j4 < 4; ++j4) {
      float4 vx = *(const float4*)(Lx + p0 + 4 * j4);
      float4 vy = *(const float4*)(Ly + p0 + 4 * j4);
      float4 vz = *(const float4*)(Lz + p0 + 4 * j4);
      *(float4*)(lx + p0 + 4 * j4) = vx;
      *(float4*)(ly + p0 + 4 * j4) = vy;
      *(float4*)(lz + p0 + 4 * j4) = vz;
      px2[2 * j4]     = (f32x2){vx.x, vx.y};
      px2[2 * j4 + 1] = (f32x2){vx.z, vx.w};
      py2[2 * j4]     = (f32x2){vy.x, vy.y};
      py2[2 * j4 + 1] = (f32x2){vy.z, vy.w};
      pz2[2 * j4]     = (f32x2){vz.x, vz.y};
      pz2[2 * j4 + 1] = (f32x2){vz.z, vz.w};
    }
    const float PINF = __int_as_float(0x7f800000);
#pragma unroll
    for (int j = 0; j < 8; ++j) dist2[j] = (f32x2){PINF, PINF};
    __syncthreads();
    float sx = lx[0], sy = ly[0], sz = lz[0];  // bootstrap: point 0

    // register shift-queue of captured winners (slot s captured by tid==s%256)
    float w0x = 0, w0y = 0, w0z = 0, w1x = 0, w1y = 0, w1z = 0;
    float w2x = 0, w2y = 0, w2z = 0, w3x = 0, w3y = 0, w3z = 0;
    if (tid == 0) { w0x = sx; w0y = sy; w0z = sz; }  // slot 0 = point 0

    for (int s = 0; s < NM - 1; ++s) {  // winners for slots 1..1023
      const f32x2 sxv = (f32x2){sx, sx};
      const f32x2 syv = (f32x2){sy, sy};
      const f32x2 szv = (f32x2){sz, sz};
      f32x2 bd2 = (f32x2){__int_as_float(0xff800000), __int_as_float(0xff800000)};
#pragma unroll
      for (int j = 0; j < 8; ++j) {
        f32x2 dx = px2[j] - sxv;
        f32x2 dy = py2[j] - syv;
        f32x2 dz = pz2[j] - szv;
        f32x2 d2 = (dx * dx + dy * dy) + dz * dz;  // contract OFF: exact numpy
        f32x2 nd = __builtin_elementwise_min(dist2[j], d2);
        dist2[j] = nd;
        bd2 = __builtin_elementwise_max(bd2, nd);
      }
      float bd = fmaxf(bd2.x, bd2.y);
      float wmax = wave_fmax(bd);
      u64 m = __ballot(bd == wmax);
      if (lane == __ffsll((long long)m) - 1) {
        // owner: first j with dist == wmax (lowest index), coords pre-barrier
        unsigned msk = 0;
#pragma unroll
        for (int j = 0; j < 8; ++j) {
          msk |= (dist2[j].x == wmax) ? (1u << (2 * j)) : 0u;
          msk |= (dist2[j].y == wmax) ? (1u << (2 * j + 1)) : 0u;
        }
        int ci = p0 + (__ffs(msk) - 1);
        red[s & 1][wid] = make_float4(wmax, lx[ci], ly[ci], lz[ci]);
      }
      __syncthreads();
      // stage 2: 4 candidates, strict > ascending wid == global first-max
      float4 c0 = red[s & 1][0], c1 = red[s & 1][1], c2 = red[s & 1][2], c3 = red[s & 1][3];
      float bdd = c0.x; sx = c0.y; sy = c0.z; sz = c0.w;
      bool g1 = c1.x > bdd; bdd = g1 ? c1.x : bdd; sx = g1 ? c1.y : sx; sy = g1 ? c1.z : sy; sz = g1 ? c1.w : sz;
      bool g2 = c2.x > bdd; bdd = g2 ? c2.x : bdd; sx = g2 ? c2.y : sx; sy = g2 ? c2.z : sy; sz = g2 ? c2.w : sz;
      bool g3 = c3.x > bdd; bdd = g3 ? c3.x : bdd; sx = g3 ? c3.y : sx; sy = g3 ? c3.z : sy; sz = g3 ? c3.w : sz;
      // capture slot s+1 into the shift queue (static indices only)
      if (tid == ((s + 1) & 255)) {
        w3x = w2x; w3y = w2y; w3z = w2z;
        w2x = w1x; w2y = w1y; w2z = w1z;
        w1x = w0x; w1y = w0y; w1z = w0z;
        w0x = sx;  w0y = sy;  w0z = sz;
      }
    }
    // thread t holds slots t(w3), t+256(w2), t+512(w1), t+768(w0)
    float* Ox = out_setloc + (b * 3 + 0) * NM;
    float* Oy = out_setloc + (b * 3 + 1) * NM;
    float* Oz = out_setloc + (b * 3 + 2) * NM;
    Ox[tid] = w3x;       Oy[tid] = w3y;       Oz[tid] = w3z;
    Ox[tid + 256] = w2x; Oy[tid + 256] = w2y; Oz[tid + 256] = w2z;
    Ox[tid + 512] = w1x; Oy[tid + 512] = w1y; Oz[tid + 512] = w1z;
    Ox[tid + 768] = w0x; Oy[tid + 768] = w0y; Oz[tid + 768] = w0z;
  }
}

// ---------- kernel B: FUSED kNN + MFMA MLP + maxpool ----------
// Phase 1: per-wave kNN (top-4 cache, exact ties) for query blockIdx*4+wid,
// results to a 512B LDS slab (no global round-trip). Phase 2: the R9 MFMA
// MLP, staging reads neighbor ids from LDS. Kills one launch + the
// device-wide knn->mlp drain bubble.

__global__ __launch_bounds__(256, 2) void knnmlp_mfma(
    const float* __restrict__ featT, const float* __restrict__ loc,
    const float* __restrict__ setloc,
    const short* __restrict__ w1b, const short* __restrict__ w2b,
    const short* __restrict__ w3b,
    const float* __restrict__ b1, const float* __restrict__ b2,
    const float* __restrict__ b3, float* __restrict__ out) {
  __shared__ __align__(16) char lds[64000];
  short* Xl = (short*)lds;              // [128][KP1] bf16; later Y2 [128][KP2]
  short* Y1 = (short*)(lds + 26624);    // [128][KP2]
  short* Wl = (short*)(lds + 45056);    // staged weight tile (<= 18432 B)
  int*   nn = (int*)(lds + 63488);      // [4][32] neighbor ids
  const int tid = threadIdx.x;
  const int lane = tid & 63;
  const int wid = tid >> 6;
  const int r = lane & 15, g = lane >> 4;

  // ======== phase 1: kNN for query q = blockIdx*4 + wid ========
  {
    const int wq = blockIdx.x * 4 + wid;
    const int bq = wq >> 10, mq1 = wq & 1023;
    const float* Sb = setloc + (size_t)bq * 3 * NM;
    float xs = Sb[mq1], ys = Sb[NM + mq1], zs = Sb[2 * NM + mq1];
    float sqs = __fadd_rn(__fadd_rn(__fmul_rn(xs, xs), __fmul_rn(ys, ys)), __fmul_rn(zs, zs));
    const float* Lx = loc + (size_t)bq * 3 * NN;
    const float* Ly = Lx + NN;
    const float* Lz = Ly + NN;
    const float INF = __int_as_float(0x7f800000);

    float k1 = INF, k2 = INF, k3 = INF, k4 = INF;
    unsigned i1 = 0xFFFFFFFFu, i2 = 0xFFFFFFFFu, i3 = 0xFFFFFFFFu, i4 = 0xFFFFFFFFu;
#pragma unroll 8
    for (int j = 0; j < 64; ++j) {
      unsigned p = (unsigned)(j * 64 + lane);
      float x = Lx[p], y = Ly[p], z = Lz[p];
      float sql = __fadd_rn(__fadd_rn(__fmul_rn(x, x), __fmul_rn(y, y)), __fmul_rn(z, z));
      float cr  = __fadd_rn(__fadd_rn(__fmul_rn(xs, x), __fmul_rn(ys, y)), __fmul_rn(zs, z));
      float d2  = __fsub_rn(__fadd_rn(sqs, sql), __fmul_rn(2.0f, cr));
      bool c1 = d2 < k1, c2 = d2 < k2, c3 = d2 < k3, c4 = d2 < k4;
      k4 = c3 ? k3 : (c4 ? d2 : k4);  i4 = c3 ? i3 : (c4 ? p : i4);
      k3 = c2 ? k2 : (c3 ? d2 : k3);  i3 = c2 ? i2 : (c3 ? p : i3);
      k2 = c1 ? k1 : (c2 ? d2 : k2);  i2 = c1 ? i1 : (c2 ? p : i2);
      k1 = c1 ? d2 : k1;              i1 = c1 ? p  : i1;
    }

    u64 used = 0;
    unsigned keep = 0;
    for (int s = 0; s < NK; ++s) {
      float wmin = wave_fmin(k1);
      u64 mask = __ballot(k1 == wmin);
      int ownerLane;
      if (__popcll(mask) > 1) {
        unsigned cand = (k1 == wmin) ? i1 : 0xFFFFFFFFu;
        unsigned minp = wave_umin(cand);
        u64 m2 = __ballot(k1 == wmin && i1 == minp);
        ownerLane = __ffsll((long long)m2) - 1;
      } else {
        ownerLane = __ffsll((long long)mask) - 1;
      }
      unsigned widx = (unsigned)__builtin_amdgcn_readlane((int)i1, ownerLane);
      if (lane == s) keep = widx;
      if (lane == ownerLane) {
        used |= 1ull << (i1 >> 6);
        k1 = k2; i1 = i2; k2 = k3; i2 = i3; k3 = k4; i3 = i4;
        k4 = INF; i4 = 0xFFFFFFFFu;
        if (__float_as_uint(k1) == 0x7f800000u) {
#pragma unroll 8
          for (int j = 0; j < 64; ++j) {
            if (!((used >> j) & 1ull)) {
              unsigned p = (unsigned)(j * 64 + lane);
              float x = Lx[p], y = Ly[p], z = Lz[p];
              float sql = __fadd_rn(__fadd_rn(__fmul_rn(x, x), __fmul_rn(y, y)), __fmul_rn(z, z));
              float cr  = __fadd_rn(__fadd_rn(__fmul_rn(xs, x), __fmul_rn(ys, y)), __fmul_rn(zs, z));
              float d2  = __fsub_rn(__fadd_rn(sqs, sql), __fmul_rn(2.0f, cr));
              bool c1 = d2 < k1, c2 = d2 < k2, c3 = d2 < k3, c4 = d2 < k4;
              k4 = c3 ? k3 : (c4 ? d2 : k4);  i4 = c3 ? i3 : (c4 ? p : i4);
              k3 = c2 ? k2 : (c3 ? d2 : k3);  i3 = c2 ? i2 : (c3 ? p : i3);
              k2 = c1 ? k1 : (c2 ? d2 : k2);  i2 = c1 ? i1 : (c2 ? p : i2);
              k1 = c1 ? d2 : k1;              i1 = c1 ? p  : i1;
            }
          }
        }
      }
    }
    if (lane < NK) nn[wid * 32 + lane] = (int)keep;
  }
  __syncthreads();

  // ======== phase 2: MFMA MLP (R9 structure; nk from LDS) ========
  // ---- stage X: gather 128 columns (2 threads/col), cvt bf16, zero-pad k ----
  {
    const int col = tid >> 1, half = tid & 1;
    const int qs = blockIdx.x * 4 + (col >> 5);
    const int bs = qs >> 10, mqs = qs & 1023;
    const int nk = nn[col];
    const float* fsrc = featT + ((size_t)(bs * NN + nk)) * 64 + half * 32;
    short* xc = Xl + col * KP1;
#pragma unroll
    for (int i = 0; i < 4; ++i) {
      float4 va = *(const float4*)(fsrc + 8 * i);
      float4 vb = *(const float4*)(fsrc + 8 * i + 4);
      int4 w;
      w.x = pk(va.x, va.y); w.y = pk(va.z, va.w);
      w.z = pk(vb.x, vb.y); w.w = pk(vb.z, vb.w);
      *(int4*)(xc + half * 32 + 8 * i) = w;
    }
    if (half) {
      const float* Lb = loc + (size_t)bs * 3 * NN;
      const float* Sb = setloc + (size_t)bs * 3 * NM;
      float rx = Lb[nk] - Sb[mqs];
      float ry = Lb[NN + nk] - Sb[NM + mqs];
      float rz = Lb[2 * NN + nk] - Sb[2 * NM + mqs];
      int2 w; w.x = pk(rx, ry); w.y = pk(rz, 0.0f);
      *(int2*)(xc + 64) = w;                       // k = 64..67
    } else {
      *(int2*)(xc + 68) = make_int2(0, 0);         // k = 68..71
#pragma unroll
      for (int i = 0; i < 4; ++i)                  // k = 72..103
        *(int4*)(xc + 72 + 8 * i) = make_int4(0, 0, 0, 0);
    }
  }
  // stage W1 tile (64*KP1 bf16 = 13312 B = 832 int4)
  for (int t = tid; t < 832; t += 256) ((int4*)Wl)[t] = ((const int4*)w1b)[t];
  __syncthreads();

  const int n0 = wid * 32;
  const int q = blockIdx.x * 4 + wid;
  const int b = q >> 10, mq = q & 1023;

  // ---- layer 1: D[64][32] = W1[64][67+] x X[67+][32], K-steps 3 ----
  f32x4 acc1[4][2];
#pragma unroll
  for (int mt = 0; mt < 4; ++mt) {
    f32x4 bv = *(const f32x4*)(b1 + mt * 16 + g * 4);
    acc1[mt][0] = bv; acc1[mt][1] = bv;
  }
#pragma unroll
  for (int kt = 0; kt < 3; ++kt) {
    const int ko = kt * 32 + g * 8;
    bf16x8 B0 = *(const bf16x8*)(Xl + (n0 + r) * KP1 + ko);
    bf16x8 B1 = *(const bf16x8*)(Xl + (n0 + 16 + r) * KP1 + ko);
#pragma unroll
    for (int mt = 0; mt < 4; ++mt) {
      bf16x8 A = *(const bf16x8*)(Wl + (mt * 16 + r) * KP1 + ko);
      acc1[mt][0] = __builtin_amdgcn_mfma_f32_16x16x32_bf16(A, B0, acc1[mt][0], 0, 0, 0);
      acc1[mt][1] = __builtin_amdgcn_mfma_f32_16x16x32_bf16(A, B1, acc1[mt][1], 0, 0, 0);
    }
  }
#pragma unroll
  for (int mt = 0; mt < 4; ++mt)
#pragma unroll
    for (int nt = 0; nt < 2; ++nt) {
      f32x4 v = acc1[mt][nt];
      v[0] = fmaxf(v[0], 0.f); v[1] = fmaxf(v[1], 0.f);
      v[2] = fmaxf(v[2], 0.f); v[3] = fmaxf(v[3], 0.f);
      int2 w; w.x = pk(v[0], v[1]); w.y = pk(v[2], v[3]);
      *(int2*)(Y1 + (n0 + nt * 16 + r) * KP2 + mt * 16 + g * 4) = w;
    }
  __syncthreads();  // all waves done reading W1 tile

  // ---- layer 2: W2[64][64] x Y1 ----
  for (int t = tid; t < 576; t += 256) ((int4*)Wl)[t] = ((const int4*)w2b)[t];
  __syncthreads();
  f32x4 acc2[4][2];
#pragma unroll
  for (int mt = 0; mt < 4; ++mt) {
    f32x4 bv = *(const f32x4*)(b2 + mt * 16 + g * 4);
    acc2[mt][0] = bv; acc2[mt][1] = bv;
  }
#pragma unroll
  for (int kt = 0; kt < 2; ++kt) {
    const int ko = kt * 32 + g * 8;
    bf16x8 B0 = *(const bf16x8*)(Y1 + (n0 + r) * KP2 + ko);
    bf16x8 B1 = *(const bf16x8*)(Y1 + (n0 + 16 + r) * KP2 + ko);
#pragma unroll
    for (int mt = 0; mt < 4; ++mt) {
      bf16x8 A = *(const bf16x8*)(Wl + (mt * 16 + r) * KP2 + ko);
      acc2[mt][0] = __builtin_amdgcn_mfma_f32_16x16x32_bf16(A, B0, acc2[mt][0], 0, 0, 0);
      acc2[mt][1] = __builtin_amdgcn_mfma_f32_16x16x32_bf16(A, B1, acc2[mt][1], 0, 0, 0);
    }
  }
#pragma unroll
  for (int mt = 0; mt < 4; ++mt)
#pragma unroll
    for (int nt = 0; nt < 2; ++nt) {
      f32x4 v = acc2[mt][nt];
      v[0] = fmaxf(v[0], 0.f); v[1] = fmaxf(v[1], 0.f);
      v[2] = fmaxf(v[2], 0.f); v[3] = fmaxf(v[3], 0.f);
      int2 w; w.x = pk(v[0], v[1]); w.y = pk(v[2], v[3]);
      *(int2*)(Xl + (n0 + nt * 16 + r) * KP2 + mt * 16 + g * 4) = w;
    }
  __syncthreads();  // all waves done reading W2 tile

  // ---- layer 3: W3[128][64] x Y2, fused relu + maxpool + store ----
  for (int t = tid; t < 1152; t += 256) ((int4*)Wl)[t] = ((const int4*)w3b)[t];
  __syncthreads();
  f32x4 acc3[8][2];
#pragma unroll
  for (int mt = 0; mt < 8; ++mt) {
    f32x4 bv = *(const f32x4*)(b3 + mt * 16 + g * 4);
    acc3[mt][0] = bv; acc3[mt][1] = bv;
  }
#pragma unroll
  for (int kt = 0; kt < 2; ++kt) {
    const int ko = kt * 32 + g * 8;
    bf16x8 B0 = *(const bf16x8*)(Xl + (n0 + r) * KP2 + ko);
    bf16x8 B1 = *(const bf16x8*)(Xl + (n0 + 16 + r) * KP2 + ko);
#pragma unroll
    for (int mt = 0; mt < 8; ++mt) {
      bf16x8 A = *(const bf16x8*)(Wl + (mt * 16 + r) * KP2 + ko);
      acc3[mt][0] = __builtin_amdgcn_mfma_f32_16x16x32_bf16(A, B0, acc3[mt][0], 0, 0, 0);
      acc3[mt][1] = __builtin_amdgcn_mfma_f32_16x16x32_bf16(A, B1, acc3[mt][1], 0, 0, 0);
    }
  }
#pragma unroll
  for (int mt = 0; mt < 8; ++mt) {
    f32x4 u = acc3[mt][0], v = acc3[mt][1];
    float m0 = fmaxf(fmaxf(u[0], v[0]), 0.0f);
    float m1 = fmaxf(fmaxf(u[1], v[1]), 0.0f);
    float m2 = fmaxf(fmaxf(u[2], v[2]), 0.0f);
    float m3 = fmaxf(fmaxf(u[3], v[3]), 0.0f);
    RED16(m0); RED16(m1); RED16(m2); RED16(m3);
    if (r == 0) {
      float* op = out + ((size_t)b * 128 + mt * 16 + g * 4) * NM + mq;
      op[0] = m0; op[NM] = m1; op[2 * NM] = m2; op[3 * NM] = m3;
    }
  }
}

// ---------- launch ----------

extern "C" void kernel_launch(void* const* d_in, const int* in_sizes, int n_in,
                              void* d_out, int out_size, void* d_ws, size_t ws_size,
                              hipStream_t stream) {
  (void)in_sizes; (void)n_in; (void)out_size; (void)ws_size;
  const float* feat = (const float*)d_in[0];
  const float* loc  = (const float*)d_in[1];
  const float* W1   = (const float*)d_in[2];
  const float* b1   = (const float*)d_in[3];
  const float* W2   = (const float*)d_in[4];
  const float* b2   = (const float*)d_in[5];
  const float* W3   = (const float*)d_in[6];
  const float* b3   = (const float*)d_in[7];
  float* out = (float*)d_out;

  char* ws = (char*)d_ws;
  float* ws_featT = (float*)(ws + 2097152);             // 16.75 MB
  short* ws_w1b   = (short*)(ws + 18874368);            // 64*104 bf16
  short* ws_w2b   = (short*)(ws + 18874368 + 13312);    // 64*72 bf16
  short* ws_w3b   = (short*)(ws + 18874368 + 22528);    // 128*72 bf16

  float* out_setfeat = out;                          // (16,128,1024)
  float* out_setloc  = out + (size_t)NB * 128 * NM;  // (16,3,1024)

  fps_fused<<<dim3(2074), dim3(256), 0, stream>>>(
      loc, out_setloc, feat, ws_featT, W1, W2, W3, ws_w1b, ws_w2b, ws_w3b);
  knnmlp_mfma<<<dim3((NB * NM) / 4), dim3(256), 0, stream>>>(
      ws_featT, loc, out_setloc, ws_w1b, ws_w2b, ws_w3b, b1, b2, b3, out_setfeat);
}

// Round 15
// 955.257 us; speedup vs baseline: 1.1298x; 1.1298x over previous
//
#include <hip/hip_runtime.h>
#include <cstdint>
#include <cstddef>

typedef unsigned long long u64;
typedef __attribute__((ext_vector_type(8))) short bf16x8;
typedef __attribute__((ext_vector_type(4))) float f32x4;
typedef __attribute__((ext_vector_type(2))) float f32x2;

#define NB 16
#define NC 64
#define NN 4096
#define NM 1024
#define NK 32
#define KP1 104
#define KP2 72

// ---------- DPP wave-reduction helpers ----------

template <int C>
__device__ __forceinline__ float dppf(float x, float ident) {
  return __int_as_float(__builtin_amdgcn_update_dpp(
      __float_as_int(ident), __float_as_int(x), C, 0xf, 0xf, false));
}

template <int C>
__device__ __forceinline__ unsigned dppu(unsigned x, unsigned ident) {
  return (unsigned)__builtin_amdgcn_update_dpp(
      (int)ident, (int)x, C, 0xf, 0xf, false);
}

__device__ __forceinline__ float wave_fmax(float x) {
  const float I = __int_as_float(0xff800000);  // -inf
  x = fmaxf(x, dppf<0x111>(x, I));
  x = fmaxf(x, dppf<0x112>(x, I));
  x = fmaxf(x, dppf<0x114>(x, I));
  x = fmaxf(x, dppf<0x118>(x, I));
  x = fmaxf(x, dppf<0x142>(x, I));  // row_bcast:15
  x = fmaxf(x, dppf<0x143>(x, I));  // row_bcast:31
  return __int_as_float(__builtin_amdgcn_readlane(__float_as_int(x), 63));
}

__device__ __forceinline__ float wave_fmin(float x) {
  const float I = __int_as_float(0x7f800000);  // +inf
  x = fminf(x, dppf<0x111>(x, I));
  x = fminf(x, dppf<0x112>(x, I));
  x = fminf(x, dppf<0x114>(x, I));
  x = fminf(x, dppf<0x118>(x, I));
  x = fminf(x, dppf<0x142>(x, I));
  x = fminf(x, dppf<0x143>(x, I));
  return __int_as_float(__builtin_amdgcn_readlane(__float_as_int(x), 63));
}

__device__ __forceinline__ unsigned wave_umin(unsigned x) {
  const unsigned I = 0xFFFFFFFFu;
  unsigned t;
  t = dppu<0x111>(x, I); x = x < t ? x : t;
  t = dppu<0x112>(x, I); x = x < t ? x : t;
  t = dppu<0x114>(x, I); x = x < t ? x : t;
  t = dppu<0x118>(x, I); x = x < t ? x : t;
  t = dppu<0x142>(x, I); x = x < t ? x : t;
  t = dppu<0x143>(x, I); x = x < t ? x : t;
  return (unsigned)__builtin_amdgcn_readlane((int)x, 63);
}

// max over 16-lane group via DPP row_ror 8/4/2/1
#define RED16(m) { m = fmaxf(m, dppf<0x128>(m, 0.f)); m = fmaxf(m, dppf<0x124>(m, 0.f)); \
                   m = fmaxf(m, dppf<0x122>(m, 0.f)); m = fmaxf(m, dppf<0x121>(m, 0.f)); }

// f32 -> bf16 (RNE), pack pair
__device__ __forceinline__ unsigned short f2bf(float f) {
  unsigned u = __float_as_uint(f);
  return (unsigned short)((u + 0x7FFFu + ((u >> 16) & 1u)) >> 16);
}
__device__ __forceinline__ int pk(float a, float b) {
  return (int)f2bf(a) | ((int)f2bf(b) << 16);
}

// ---------- kernel A: FUSED fps + transpose + w_prep (R13, verbatim) ----------

__global__ __launch_bounds__(256) void fps_fused(
    const float* __restrict__ loc, float* __restrict__ out_setloc,
    const float* __restrict__ feat, float* __restrict__ featT,
    const float* __restrict__ W1, const float* __restrict__ W2,
    const float* __restrict__ W3, short* __restrict__ w1b,
    short* __restrict__ w2b, short* __restrict__ w3b) {
  __shared__ __align__(16) float lx[NN];
  __shared__ __align__(16) float ly[NN];
  __shared__ __align__(16) float lz[NN];
  __shared__ float4 red[2][4];
  const int tid = threadIdx.x;

  if (blockIdx.x >= 16) {
    if (blockIdx.x < 2064) {
      // transpose role: 2048 elements per block
      const int base = (blockIdx.x - 16) * 2048;
#pragma unroll
      for (int it = 0; it < 8; ++it) {
        int g = base + it * 256 + tid;
        int c = g & 63;
        int n = (g >> 6) & 4095;
        int b = g >> 18;
        featT[g] = feat[((size_t)(b * NC + c)) * NN + n];
      }
    } else {
      // w_prep role: 20480 elements over 10 blocks
      const int base = (blockIdx.x - 2064) * 2048;
#pragma unroll
      for (int it = 0; it < 8; ++it) {
        int gg = base + it * 256 + tid;
        if (gg < 64 * KP1) {
          int r = gg / KP1, k = gg - r * KP1;
          w1b[gg] = (k < 67) ? (short)f2bf(W1[r * 67 + k]) : (short)0;
        } else if (gg < 64 * KP1 + 64 * KP2) {
          int g2 = gg - 64 * KP1;
          int r = g2 / KP2, k = g2 - r * KP2;
          w2b[g2] = (k < 64) ? (short)f2bf(W2[r * 64 + k]) : (short)0;
        } else if (gg < 64 * KP1 + 64 * KP2 + 128 * KP2) {
          int g3 = gg - 64 * KP1 - 64 * KP2;
          int r = g3 / KP2, k = g3 - r * KP2;
          w3b[g3] = (k < 64) ? (short)f2bf(W3[r * 64 + k]) : (short)0;
        }
      }
    }
    return;
  }

  // ---- fps role: one batch per block ----
  {
    // CRITICAL: no fma contraction -- the discrete argmax must reproduce
    // numpy's exact per-op rounding (mul, add, add; left-assoc).
#pragma clang fp contract(off)
    const int b = blockIdx.x;
    const int lane = tid & 63, wid = tid >> 6;
    const float* Lx = loc + (size_t)b * 3 * NN;
    const float* Ly = Lx + NN;
    const float* Lz = Ly + NN;
    const int p0 = tid * 16;
    f32x2 px2[8], py2[8], pz2[8], dist2[8];
#pragma unroll
    for (int j4 = 0; j4 < 4; ++j4) {
      float4 vx = *(const float4*)(Lx + p0 + 4 * j4);
      float4 vy = *(const float4*)(Ly + p0 + 4 * j4);
      float4 vz = *(const float4*)(Lz + p0 + 4 * j4);
      *(float4*)(lx + p0 + 4 * j4) = vx;
      *(float4*)(ly + p0 + 4 * j4) = vy;
      *(float4*)(lz + p0 + 4 * j4) = vz;
      px2[2 * j4]     = (f32x2){vx.x, vx.y};
      px2[2 * j4 + 1] = (f32x2){vx.z, vx.w};
      py2[2 * j4]     = (f32x2){vy.x, vy.y};
      py2[2 * j4 + 1] = (f32x2){vy.z, vy.w};
      pz2[2 * j4]     = (f32x2){vz.x, vz.y};
      pz2[2 * j4 + 1] = (f32x2){vz.z, vz.w};
    }
    const float PINF = __int_as_float(0x7f800000);
#pragma unroll
    for (int j = 0; j < 8; ++j) dist2[j] = (f32x2){PINF, PINF};
    __syncthreads();
    float sx = lx[0], sy = ly[0], sz = lz[0];  // bootstrap: point 0

    // register shift-queue of captured winners (slot s captured by tid==s%256)
    float w0x = 0, w0y = 0, w0z = 0, w1x = 0, w1y = 0, w1z = 0;
    float w2x = 0, w2y = 0, w2z = 0, w3x = 0, w3y = 0, w3z = 0;
    if (tid == 0) { w0x = sx; w0y = sy; w0z = sz; }  // slot 0 = point 0

    for (int s = 0; s < NM - 1; ++s) {  // winners for slots 1..1023
      const f32x2 sxv = (f32x2){sx, sx};
      const f32x2 syv = (f32x2){sy, sy};
      const f32x2 szv = (f32x2){sz, sz};
      f32x2 bd2 = (f32x2){__int_as_float(0xff800000), __int_as_float(0xff800000)};
#pragma unroll
      for (int j = 0; j < 8; ++j) {
        f32x2 dx = px2[j] - sxv;
        f32x2 dy = py2[j] - syv;
        f32x2 dz = pz2[j] - szv;
        f32x2 d2 = (dx * dx + dy * dy) + dz * dz;  // contract OFF: exact numpy
        f32x2 nd = __builtin_elementwise_min(dist2[j], d2);
        dist2[j] = nd;
        bd2 = __builtin_elementwise_max(bd2, nd);
      }
      float bd = fmaxf(bd2.x, bd2.y);
      float wmax = wave_fmax(bd);
      u64 m = __ballot(bd == wmax);
      if (lane == __ffsll((long long)m) - 1) {
        // owner: first j with dist == wmax (lowest index), coords pre-barrier
        unsigned msk = 0;
#pragma unroll
        for (int j = 0; j < 8; ++j) {
          msk |= (dist2[j].x == wmax) ? (1u << (2 * j)) : 0u;
          msk |= (dist2[j].y == wmax) ? (1u << (2 * j + 1)) : 0u;
        }
        int ci = p0 + (__ffs(msk) - 1);
        red[s & 1][wid] = make_float4(wmax, lx[ci], ly[ci], lz[ci]);
      }
      __syncthreads();
      // stage 2: 4 candidates, strict > ascending wid == global first-max
      float4 c0 = red[s & 1][0], c1 = red[s & 1][1], c2 = red[s & 1][2], c3 = red[s & 1][3];
      float bdd = c0.x; sx = c0.y; sy = c0.z; sz = c0.w;
      bool g1 = c1.x > bdd; bdd = g1 ? c1.x : bdd; sx = g1 ? c1.y : sx; sy = g1 ? c1.z : sy; sz = g1 ? c1.w : sz;
      bool g2 = c2.x > bdd; bdd = g2 ? c2.x : bdd; sx = g2 ? c2.y : sx; sy = g2 ? c2.z : sy; sz = g2 ? c2.w : sz;
      bool g3 = c3.x > bdd; bdd = g3 ? c3.x : bdd; sx = g3 ? c3.y : sx; sy = g3 ? c3.z : sy; sz = g3 ? c3.w : sz;
      // capture slot s+1 into the shift queue (static indices only)
      if (tid == ((s + 1) & 255)) {
        w3x = w2x; w3y = w2y; w3z = w2z;
        w2x = w1x; w2y = w1y; w2z = w1z;
        w1x = w0x; w1y = w0y; w1z = w0z;
        w0x = sx;  w0y = sy;  w0z = sz;
      }
    }
    // thread t holds slots t(w3), t+256(w2), t+512(w1), t+768(w0)
    float* Ox = out_setloc + (b * 3 + 0) * NM;
    float* Oy = out_setloc + (b * 3 + 1) * NM;
    float* Oz = out_setloc + (b * 3 + 2) * NM;
    Ox[tid] = w3x;       Oy[tid] = w3y;       Oz[tid] = w3z;
    Ox[tid + 256] = w2x; Oy[tid + 256] = w2y; Oz[tid + 256] = w2z;
    Ox[tid + 512] = w1x; Oy[tid + 512] = w1y; Oz[tid + 512] = w1z;
    Ox[tid + 768] = w0x; Oy[tid + 768] = w0y; Oz[tid + 768] = w0z;
  }
}

// ---------- kernel B: kNN (one wave per query, per-lane TOP-4 cache) ----------

__global__ __launch_bounds__(256) void knn_kernel(const float* __restrict__ loc,
                                                  const float* __restrict__ setloc,
                                                  int* __restrict__ ws_knn) {
  const int wq = blockIdx.x * 4 + (threadIdx.x >> 6);  // query id, < NB*NM
  const int lane = threadIdx.x & 63;
  const int b = wq >> 10, mq = wq & 1023;
  const float* Sb = setloc + (size_t)b * 3 * NM;
  float xs = Sb[mq], ys = Sb[NM + mq], zs = Sb[2 * NM + mq];
  float sqs = __fadd_rn(__fadd_rn(__fmul_rn(xs, xs), __fmul_rn(ys, ys)), __fmul_rn(zs, zs));
  const float* Lx = loc + (size_t)b * 3 * NN;
  const float* Ly = Lx + NN;
  const float* Lz = Ly + NN;
  const float INF = __int_as_float(0x7f800000);

  float k1 = INF, k2 = INF, k3 = INF, k4 = INF;
  unsigned i1 = 0xFFFFFFFFu, i2 = 0xFFFFFFFFu, i3 = 0xFFFFFFFFu, i4 = 0xFFFFFFFFu;
#pragma unroll 8
  for (int j = 0; j < 64; ++j) {
    unsigned p = (unsigned)(j * 64 + lane);
    float x = Lx[p], y = Ly[p], z = Lz[p];
    float sql = __fadd_rn(__fadd_rn(__fmul_rn(x, x), __fmul_rn(y, y)), __fmul_rn(z, z));
    float cr  = __fadd_rn(__fadd_rn(__fmul_rn(xs, x), __fmul_rn(ys, y)), __fmul_rn(zs, z));
    float d2  = __fsub_rn(__fadd_rn(sqs, sql), __fmul_rn(2.0f, cr));
    bool c1 = d2 < k1, c2 = d2 < k2, c3 = d2 < k3, c4 = d2 < k4;
    k4 = c3 ? k3 : (c4 ? d2 : k4);  i4 = c3 ? i3 : (c4 ? p : i4);
    k3 = c2 ? k2 : (c3 ? d2 : k3);  i3 = c2 ? i2 : (c3 ? p : i3);
    k2 = c1 ? k1 : (c2 ? d2 : k2);  i2 = c1 ? i1 : (c2 ? p : i2);
    k1 = c1 ? d2 : k1;              i1 = c1 ? p  : i1;
  }

  u64 used = 0;
  unsigned keep = 0;
  for (int s = 0; s < NK; ++s) {
    float wmin = wave_fmin(k1);
    u64 mask = __ballot(k1 == wmin);
    int ownerLane;
    if (__popcll(mask) > 1) {
      unsigned cand = (k1 == wmin) ? i1 : 0xFFFFFFFFu;
      unsigned minp = wave_umin(cand);
      u64 m2 = __ballot(k1 == wmin && i1 == minp);
      ownerLane = __ffsll((long long)m2) - 1;
    } else {
      ownerLane = __ffsll((long long)mask) - 1;
    }
    unsigned widx = (unsigned)__builtin_amdgcn_readlane((int)i1, ownerLane);
    if (lane == s) keep = widx;
    if (lane == ownerLane) {
      used |= 1ull << (i1 >> 6);
      k1 = k2; i1 = i2; k2 = k3; i2 = i3; k3 = k4; i3 = i4;
      k4 = INF; i4 = 0xFFFFFFFFu;
      if (__float_as_uint(k1) == 0x7f800000u) {
#pragma unroll 8
        for (int j = 0; j < 64; ++j) {
          if (!((used >> j) & 1ull)) {
            unsigned p = (unsigned)(j * 64 + lane);
            float x = Lx[p], y = Ly[p], z = Lz[p];
            float sql = __fadd_rn(__fadd_rn(__fmul_rn(x, x), __fmul_rn(y, y)), __fmul_rn(z, z));
            float cr  = __fadd_rn(__fadd_rn(__fmul_rn(xs, x), __fmul_rn(ys, y)), __fmul_rn(zs, z));
            float d2  = __fsub_rn(__fadd_rn(sqs, sql), __fmul_rn(2.0f, cr));
            bool c1 = d2 < k1, c2 = d2 < k2, c3 = d2 < k3, c4 = d2 < k4;
            k4 = c3 ? k3 : (c4 ? d2 : k4);  i4 = c3 ? i3 : (c4 ? p : i4);
            k3 = c2 ? k2 : (c3 ? d2 : k3);  i3 = c2 ? i2 : (c3 ? p : i3);
            k2 = c1 ? k1 : (c2 ? d2 : k2);  i2 = c1 ? i1 : (c2 ? p : i2);
            k1 = c1 ? d2 : k1;              i1 = c1 ? p  : i1;
          }
        }
      }
    }
  }
  if (lane < NK) ws_knn[(size_t)wq * NK + lane] = (int)keep;
}

// ---------- kernel C: MFMA gather + 3-layer MLP + maxpool (R9, verbatim) ----------

__global__ __launch_bounds__(256, 2) void mlp_mfma(
    const float* __restrict__ featT, const float* __restrict__ loc,
    const float* __restrict__ setloc, const int* __restrict__ ws_knn,
    const short* __restrict__ w1b, const short* __restrict__ w2b,
    const short* __restrict__ w3b,
    const float* __restrict__ b1, const float* __restrict__ b2,
    const float* __restrict__ b3, float* __restrict__ out) {
  __shared__ __align__(16) char lds[63488];
  short* Xl = (short*)lds;              // [128][KP1] bf16; later Y2 [128][KP2]
  short* Y1 = (short*)(lds + 26624);    // [128][KP2]
  short* Wl = (short*)(lds + 45056);    // staged weight tile (<= 18432 B)
  const int tid = threadIdx.x;
  const int lane = tid & 63;
  const int wid = tid >> 6;
  const int r = lane & 15, g = lane >> 4;

  // ---- stage X: gather 128 columns (2 threads/col), cvt bf16, zero-pad k ----
  {
    const int col = tid >> 1, half = tid & 1;
    const int qs = blockIdx.x * 4 + (col >> 5);
    const int bs = qs >> 10, mqs = qs & 1023;
    const int nk = ws_knn[(size_t)qs * NK + (col & 31)];
    const float* fsrc = featT + ((size_t)(bs * NN + nk)) * 64 + half * 32;
    short* xc = Xl + col * KP1;
#pragma unroll
    for (int i = 0; i < 4; ++i) {
      float4 va = *(const float4*)(fsrc + 8 * i);
      float4 vb = *(const float4*)(fsrc + 8 * i + 4);
      int4 w;
      w.x = pk(va.x, va.y); w.y = pk(va.z, va.w);
      w.z = pk(vb.x, vb.y); w.w = pk(vb.z, vb.w);
      *(int4*)(xc + half * 32 + 8 * i) = w;
    }
    if (half) {
      const float* Lb = loc + (size_t)bs * 3 * NN;
      const float* Sb = setloc + (size_t)bs * 3 * NM;
      float rx = Lb[nk] - Sb[mqs];
      float ry = Lb[NN + nk] - Sb[NM + mqs];
      float rz = Lb[2 * NN + nk] - Sb[2 * NM + mqs];
      int2 w; w.x = pk(rx, ry); w.y = pk(rz, 0.0f);
      *(int2*)(xc + 64) = w;                       // k = 64..67
    } else {
      *(int2*)(xc + 68) = make_int2(0, 0);         // k = 68..71
#pragma unroll
      for (int i = 0; i < 4; ++i)                  // k = 72..103
        *(int4*)(xc + 72 + 8 * i) = make_int4(0, 0, 0, 0);
    }
  }
  // stage W1 tile (64*KP1 bf16 = 13312 B = 832 int4)
  for (int t = tid; t < 832; t += 256) ((int4*)Wl)[t] = ((const int4*)w1b)[t];
  __syncthreads();

  const int n0 = wid * 32;
  const int q = blockIdx.x * 4 + wid;
  const int b = q >> 10, mq = q & 1023;

  // ---- layer 1: D[64][32] = W1[64][67+] x X[67+][32], K-steps 3 ----
  f32x4 acc1[4][2];
#pragma unroll
  for (int mt = 0; mt < 4; ++mt) {
    f32x4 bv = *(const f32x4*)(b1 + mt * 16 + g * 4);
    acc1[mt][0] = bv; acc1[mt][1] = bv;
  }
#pragma unroll
  for (int kt = 0; kt < 3; ++kt) {
    const int ko = kt * 32 + g * 8;
    bf16x8 B0 = *(const bf16x8*)(Xl + (n0 + r) * KP1 + ko);
    bf16x8 B1 = *(const bf16x8*)(Xl + (n0 + 16 + r) * KP1 + ko);
#pragma unroll
    for (int mt = 0; mt < 4; ++mt) {
      bf16x8 A = *(const bf16x8*)(Wl + (mt * 16 + r) * KP1 + ko);
      acc1[mt][0] = __builtin_amdgcn_mfma_f32_16x16x32_bf16(A, B0, acc1[mt][0], 0, 0, 0);
      acc1[mt][1] = __builtin_amdgcn_mfma_f32_16x16x32_bf16(A, B1, acc1[mt][1], 0, 0, 0);
    }
  }
#pragma unroll
  for (int mt = 0; mt < 4; ++mt)
#pragma unroll
    for (int nt = 0; nt < 2; ++nt) {
      f32x4 v = acc1[mt][nt];
      v[0] = fmaxf(v[0], 0.f); v[1] = fmaxf(v[1], 0.f);
      v[2] = fmaxf(v[2], 0.f); v[3] = fmaxf(v[3], 0.f);
      int2 w; w.x = pk(v[0], v[1]); w.y = pk(v[2], v[3]);
      *(int2*)(Y1 + (n0 + nt * 16 + r) * KP2 + mt * 16 + g * 4) = w;
    }
  __syncthreads();  // all waves done reading W1 tile

  // ---- layer 2: W2[64][64] x Y1 ----
  for (int t = tid; t < 576; t += 256) ((int4*)Wl)[t] = ((const int4*)w2b)[t];
  __syncthreads();
  f32x4 acc2[4][2];
#pragma unroll
  for (int mt = 0; mt < 4; ++mt) {
    f32x4 bv = *(const f32x4*)(b2 + mt * 16 + g * 4);
    acc2[mt][0] = bv; acc2[mt][1] = bv;
  }
#pragma unroll
  for (int kt = 0; kt < 2; ++kt) {
    const int ko = kt * 32 + g * 8;
    bf16x8 B0 = *(const bf16x8*)(Y1 + (n0 + r) * KP2 + ko);
    bf16x8 B1 = *(const bf16x8*)(Y1 + (n0 + 16 + r) * KP2 + ko);
#pragma unroll
    for (int mt = 0; mt < 4; ++mt) {
      bf16x8 A = *(const bf16x8*)(Wl + (mt * 16 + r) * KP2 + ko);
      acc2[mt][0] = __builtin_amdgcn_mfma_f32_16x16x32_bf16(A, B0, acc2[mt][0], 0, 0, 0);
      acc2[mt][1] = __builtin_amdgcn_mfma_f32_16x16x32_bf16(A, B1, acc2[mt][1], 0, 0, 0);
    }
  }
#pragma unroll
  for (int mt = 0; mt < 4; ++mt)
#pragma unroll
    for (int nt = 0; nt < 2; ++nt) {
      f32x4 v = acc2[mt][nt];
      v[0] = fmaxf(v[0], 0.f); v[1] = fmaxf(v[1], 0.f);
      v[2] = fmaxf(v[2], 0.f); v[3] = fmaxf(v[3], 0.f);
      int2 w; w.x = pk(v[0], v[1]); w.y = pk(v[2], v[3]);
      *(int2*)(Xl + (n0 + nt * 16 + r) * KP2 + mt * 16 + g * 4) = w;
    }
  __syncthreads();  // all waves done reading W2 tile

  // ---- layer 3: W3[128][64] x Y2, fused relu + maxpool + store ----
  for (int t = tid; t < 1152; t += 256) ((int4*)Wl)[t] = ((const int4*)w3b)[t];
  __syncthreads();
  f32x4 acc3[8][2];
#pragma unroll
  for (int mt = 0; mt < 8; ++mt) {
    f32x4 bv = *(const f32x4*)(b3 + mt * 16 + g * 4);
    acc3[mt][0] = bv; acc3[mt][1] = bv;
  }
#pragma unroll
  for (int kt = 0; kt < 2; ++kt) {
    const int ko = kt * 32 + g * 8;
    bf16x8 B0 = *(const bf16x8*)(Xl + (n0 + r) * KP2 + ko);
    bf16x8 B1 = *(const bf16x8*)(Xl + (n0 + 16 + r) * KP2 + ko);
#pragma unroll
    for (int mt = 0; mt < 8; ++mt) {
      bf16x8 A = *(const bf16x8*)(Wl + (mt * 16 + r) * KP2 + ko);
      acc3[mt][0] = __builtin_amdgcn_mfma_f32_16x16x32_bf16(A, B0, acc3[mt][0], 0, 0, 0);
      acc3[mt][1] = __builtin_amdgcn_mfma_f32_16x16x32_bf16(A, B1, acc3[mt][1], 0, 0, 0);
    }
  }
#pragma unroll
  for (int mt = 0; mt < 8; ++mt) {
    f32x4 u = acc3[mt][0], v = acc3[mt][1];
    float m0 = fmaxf(fmaxf(u[0], v[0]), 0.0f);
    float m1 = fmaxf(fmaxf(u[1], v[1]), 0.0f);
    float m2 = fmaxf(fmaxf(u[2], v[2]), 0.0f);
    float m3 = fmaxf(fmaxf(u[3], v[3]), 0.0f);
    RED16(m0); RED16(m1); RED16(m2); RED16(m3);
    if (r == 0) {
      float* op = out + ((size_t)b * 128 + mt * 16 + g * 4) * NM + mq;
      op[0] = m0; op[NM] = m1; op[2 * NM] = m2; op[3 * NM] = m3;
    }
  }
}

// ---------- launch ----------

extern "C" void kernel_launch(void* const* d_in, const int* in_sizes, int n_in,
                              void* d_out, int out_size, void* d_ws, size_t ws_size,
                              hipStream_t stream) {
  (void)in_sizes; (void)n_in; (void)out_size; (void)ws_size;
  const float* feat = (const float*)d_in[0];
  const float* loc  = (const float*)d_in[1];
  const float* W1   = (const float*)d_in[2];
  const float* b1   = (const float*)d_in[3];
  const float* W2   = (const float*)d_in[4];
  const float* b2   = (const float*)d_in[5];
  const float* W3   = (const float*)d_in[6];
  const float* b3   = (const float*)d_in[7];
  float* out = (float*)d_out;

  char* ws = (char*)d_ws;
  int*   ws_knn   = (int*)ws;                           // 2 MB
  float* ws_featT = (float*)(ws + 2097152);             // 16.75 MB
  short* ws_w1b   = (short*)(ws + 18874368);            // 64*104 bf16
  short* ws_w2b   = (short*)(ws + 18874368 + 13312);    // 64*72 bf16
  short* ws_w3b   = (short*)(ws + 18874368 + 22528);    // 128*72 bf16

  float* out_setfeat = out;                          // (16,128,1024)
  float* out_setloc  = out + (size_t)NB * 128 * NM;  // (16,3,1024)

  fps_fused<<<dim3(2074), dim3(256), 0, stream>>>(
      loc, out_setloc, feat, ws_featT, W1, W2, W3, ws_w1b, ws_w2b, ws_w3b);
  knn_kernel<<<dim3((NB * NM) / 4), dim3(256), 0, stream>>>(loc, out_setloc, ws_knn);
  mlp_mfma<<<dim3((NB * NM) / 4), dim3(256), 0, stream>>>(
      ws_featT, loc, out_setloc, ws_knn, ws_w1b, ws_w2b, ws_w3b, b1, b2, b3, out_setfeat);
}